// Round 2
// baseline (309.139 us; speedup 1.0000x reference)
//
#include <hip/hip_runtime.h>
#include <hip/hip_bf16.h>

#define S_LEN 2048
#define NHEAD 16
#define HDIM 64
#define HID 1024

typedef __attribute__((ext_vector_type(8))) short bf16x8;
typedef __attribute__((ext_vector_type(4))) float f32x4;

__device__ __forceinline__ unsigned short f2bf(float x) {
    unsigned int u = __builtin_bit_cast(unsigned int, x);
    u = (u + 0x7fffu + ((u >> 16) & 1u)) >> 16;
    return (unsigned short)u;
}
__device__ __forceinline__ float bf2f(unsigned short s) {
    unsigned int u = ((unsigned int)s) << 16;
    return __builtin_bit_cast(float, u);
}

// ---------------- prep: f32 -> bf16 convert (vectorized) ----------------
__global__ void cvt_kernel(const float* __restrict__ src, short* __restrict__ dst, int n4) {
    int i = blockIdx.x * blockDim.x + threadIdx.x;
    if (i < n4) {
        float4 v = reinterpret_cast<const float4*>(src)[i];
        short4 o;
        o.x = (short)f2bf(v.x); o.y = (short)f2bf(v.y);
        o.z = (short)f2bf(v.z); o.w = (short)f2bf(v.w);
        reinterpret_cast<short4*>(dst)[i] = o;
    }
}

// ------------- prep: tiled transpose f32 [R][C] -> bf16 [C][R] ----------
__global__ void transpose_bf16(const float* __restrict__ src, short* __restrict__ dst,
                               int R, int C) {
    __shared__ float tile[32][33];
    int bx = blockIdx.x * 32;  // col base in src
    int by = blockIdx.y * 32;  // row base in src
    int tx = threadIdx.x, ty = threadIdx.y;  // 32 x 8
    #pragma unroll
    for (int i = ty; i < 32; i += 8)
        tile[i][tx] = src[(size_t)(by + i) * C + bx + tx];
    __syncthreads();
    #pragma unroll
    for (int i = ty; i < 32; i += 8)
        dst[(size_t)(bx + i) * R + by + tx] = (short)f2bf(tile[tx][i]);
}

// ---------------- QKV GEMM: [4096,1024] @ [1024,3072] -------------------
// WT layout: [3072 rows n][1024 k] (rows 0..1023 = Wq^T, 1024.. = Wk^T, 2048.. = Wv^T)
__global__ __launch_bounds__(256, 2)
void gemm_qkv(const short* __restrict__ xb, const short* __restrict__ WT,
              const float* __restrict__ bq, const float* __restrict__ bk,
              const float* __restrict__ bv,
              short* __restrict__ Qb, short* __restrict__ Kb, short* __restrict__ Vb) {
    const int LD = 40;
    __shared__ short Al[128 * LD];
    __shared__ short Bl[128 * LD];
    int mb = blockIdx.x, nb = blockIdx.y;
    int tid = threadIdx.x;
    int wave = tid >> 6, lane = tid & 63;
    int wm = wave >> 1, wn = wave & 1;
    int lr = lane & 15, lg = lane >> 4;

    f32x4 acc[4][4] = {};

    for (int ks = 0; ks < 32; ++ks) {
        __syncthreads();
        for (int cid = tid; cid < 512; cid += 256) {
            int r = cid >> 2;
            int c8 = (cid & 3) * 8;
            *(bf16x8*)&Al[r * LD + c8] =
                *(const bf16x8*)&xb[(size_t)(mb * 128 + r) * 1024 + ks * 32 + c8];
            *(bf16x8*)&Bl[r * LD + c8] =
                *(const bf16x8*)&WT[(size_t)(nb * 128 + r) * 1024 + ks * 32 + c8];
        }
        __syncthreads();
        bf16x8 af[4], bfr[4];
        #pragma unroll
        for (int t = 0; t < 4; t++)
            af[t] = *(bf16x8*)&Al[(wm * 64 + t * 16 + lr) * LD + lg * 8];
        #pragma unroll
        for (int t = 0; t < 4; t++)
            bfr[t] = *(bf16x8*)&Bl[(wn * 64 + t * 16 + lr) * LD + lg * 8];
        #pragma unroll
        for (int i = 0; i < 4; i++)
            #pragma unroll
            for (int jn = 0; jn < 4; jn++)
                acc[i][jn] = __builtin_amdgcn_mfma_f32_16x16x32_bf16(af[i], bfr[jn], acc[i][jn], 0, 0, 0);
    }

    #pragma unroll
    for (int jn = 0; jn < 4; jn++) {
        int n = nb * 128 + wn * 64 + jn * 16 + lr;
        int which = n >> 10;
        int n1 = n & 1023;
        const float* bias = (which == 0) ? bq : (which == 1) ? bk : bv;
        short* out = (which == 0) ? Qb : (which == 1) ? Kb : Vb;
        float bv_ = bias[n1];
        #pragma unroll
        for (int i = 0; i < 4; i++) {
            #pragma unroll
            for (int j = 0; j < 4; j++) {
                int mm = mb * 128 + wm * 64 + i * 16 + lg * 4 + j;
                out[(size_t)mm * 1024 + n1] = (short)f2bf(acc[i][jn][j] + bv_);
            }
        }
    }
}

// ---------------- flash attention with antisymmetric flow ---------------
// flow[q,k] = (Q_q.K_k - K_q.Q_k)/8 ; softmax over k ; O = P V
__global__ __launch_bounds__(256, 2)
void attn_kernel(const short* __restrict__ Qb, const short* __restrict__ Kb,
                 const short* __restrict__ Vb, short* __restrict__ Fb) {
    const int LD = 80;
    __shared__ short Kt[64 * LD];
    __shared__ short Qt[64 * LD];
    __shared__ short Vt[64 * LD];          // transposed: Vt[dv][key]
    __shared__ short Pl[4][16 * LD];

    int bid = blockIdx.x;
    int qb = bid & 31;
    int h = (bid >> 5) & 15;
    int b = bid >> 9;
    int tid = threadIdx.x;
    int wave = tid >> 6, lane = tid & 63;
    int lr = lane & 15, lg = lane >> 4;

    // hoisted per-wave Q/K fragments (A-side), rows = wave's 16 q-rows
    size_t rowbase = ((size_t)(b * S_LEN + qb * 64 + wave * 16 + lr)) * HID + h * HDIM;
    bf16x8 Qf[2], Kf[2];
    #pragma unroll
    for (int c = 0; c < 2; c++) {
        Qf[c] = *(const bf16x8*)(Qb + rowbase + c * 32 + lg * 8);
        Kf[c] = *(const bf16x8*)(Kb + rowbase + c * 32 + lg * 8);
    }

    f32x4 O[4] = {};
    float m[4], l[4];
    #pragma unroll
    for (int j = 0; j < 4; j++) { m[j] = -1e30f; l[j] = 0.f; }

    for (int kt = 0; kt < 32; ++kt) {
        __syncthreads();
        for (int cid = tid; cid < 512; cid += 256) {
            int r = cid >> 3;
            int c8 = (cid & 7) * 8;
            size_t g = ((size_t)(b * S_LEN + kt * 64 + r)) * HID + h * HDIM + c8;
            bf16x8 kv = *(const bf16x8*)(Kb + g);
            bf16x8 qv = *(const bf16x8*)(Qb + g);
            bf16x8 vv = *(const bf16x8*)(Vb + g);
            *(bf16x8*)&Kt[r * LD + c8] = kv;
            *(bf16x8*)&Qt[r * LD + c8] = qv;
            #pragma unroll
            for (int e = 0; e < 8; e++) Vt[(c8 + e) * LD + r] = vv[e];
        }
        __syncthreads();

        f32x4 S1[4] = {}; f32x4 S2[4] = {};
        #pragma unroll
        for (int t = 0; t < 4; t++) {
            #pragma unroll
            for (int c = 0; c < 2; c++) {
                bf16x8 kf = *(bf16x8*)&Kt[(t * 16 + lr) * LD + c * 32 + lg * 8];
                bf16x8 qf = *(bf16x8*)&Qt[(t * 16 + lr) * LD + c * 32 + lg * 8];
                S1[t] = __builtin_amdgcn_mfma_f32_16x16x32_bf16(Qf[c], kf, S1[t], 0, 0, 0);
                S2[t] = __builtin_amdgcn_mfma_f32_16x16x32_bf16(Kf[c], qf, S2[t], 0, 0, 0);
            }
        }

        // online softmax; lane holds rows (lg*4+j), cols (t*16+lr)
        float s[4][4], pm[4];
        #pragma unroll
        for (int j = 0; j < 4; j++) {
            pm[j] = -1e30f;
            #pragma unroll
            for (int t = 0; t < 4; t++) {
                s[t][j] = (S1[t][j] - S2[t][j]) * 0.125f;
                pm[j] = fmaxf(pm[j], s[t][j]);
            }
        }
        #pragma unroll
        for (int off = 1; off < 16; off <<= 1)
            #pragma unroll
            for (int j = 0; j < 4; j++) pm[j] = fmaxf(pm[j], __shfl_xor(pm[j], off));
        float alpha[4], rs[4];
        #pragma unroll
        for (int j = 0; j < 4; j++) {
            float mn = fmaxf(m[j], pm[j]);
            alpha[j] = __expf(m[j] - mn);
            m[j] = mn;
            rs[j] = 0.f;
        }
        #pragma unroll
        for (int t = 0; t < 4; t++) {
            #pragma unroll
            for (int j = 0; j < 4; j++) {
                float p = __expf(s[t][j] - m[j]);
                rs[j] += p;
                Pl[wave][(lg * 4 + j) * LD + t * 16 + lr] = (short)f2bf(p);
            }
        }
        #pragma unroll
        for (int off = 1; off < 16; off <<= 1)
            #pragma unroll
            for (int j = 0; j < 4; j++) rs[j] += __shfl_xor(rs[j], off);
        #pragma unroll
        for (int j = 0; j < 4; j++) l[j] = l[j] * alpha[j] + rs[j];
        #pragma unroll
        for (int dvt = 0; dvt < 4; dvt++)
            #pragma unroll
            for (int j = 0; j < 4; j++) O[dvt][j] *= alpha[j];

        // PV: A = P rows (lane&15), B = Vt rows dv
        #pragma unroll
        for (int c = 0; c < 2; c++) {
            bf16x8 pf = *(bf16x8*)&Pl[wave][lr * LD + c * 32 + lg * 8];
            #pragma unroll
            for (int dvt = 0; dvt < 4; dvt++) {
                bf16x8 vf = *(bf16x8*)&Vt[(dvt * 16 + lr) * LD + c * 32 + lg * 8];
                O[dvt] = __builtin_amdgcn_mfma_f32_16x16x32_bf16(pf, vf, O[dvt], 0, 0, 0);
            }
        }
    }

    #pragma unroll
    for (int dvt = 0; dvt < 4; dvt++) {
        #pragma unroll
        for (int j = 0; j < 4; j++) {
            int q = qb * 64 + wave * 16 + lg * 4 + j;
            int dv = dvt * 16 + lr;
            float o = O[dvt][j] / l[j];
            Fb[((size_t)(b * S_LEN + q)) * HID + h * HDIM + dv] = (short)f2bf(o);
        }
    }
}

// ------- gate GEMM (K=2048 over [xb | flowed]) + sigmoid + residual -----
// writes y (pre-LN, fp32) directly into d_out; LN then normalizes in place
__global__ __launch_bounds__(256, 2)
void gemm_gate(const short* __restrict__ xb, const short* __restrict__ fb,
               const short* __restrict__ WgT, const float* __restrict__ bg,
               const float* __restrict__ x, float* __restrict__ y) {
    const int LD = 40;
    __shared__ short Al[128 * LD];
    __shared__ short Bl[128 * LD];
    int mb = blockIdx.x, nb = blockIdx.y;
    int tid = threadIdx.x;
    int wave = tid >> 6, lane = tid & 63;
    int wm = wave >> 1, wn = wave & 1;
    int lr = lane & 15, lg = lane >> 4;

    f32x4 acc[4][4] = {};

    for (int ks = 0; ks < 64; ++ks) {
        int kg = ks * 32;
        __syncthreads();
        for (int cid = tid; cid < 512; cid += 256) {
            int r = cid >> 2;
            int c8 = (cid & 3) * 8;
            const short* A = (kg < 1024)
                ? &xb[(size_t)(mb * 128 + r) * 1024 + kg + c8]
                : &fb[(size_t)(mb * 128 + r) * 1024 + (kg - 1024) + c8];
            *(bf16x8*)&Al[r * LD + c8] = *(const bf16x8*)A;
            *(bf16x8*)&Bl[r * LD + c8] =
                *(const bf16x8*)&WgT[(size_t)(nb * 128 + r) * 2048 + kg + c8];
        }
        __syncthreads();
        bf16x8 af[4], bfr[4];
        #pragma unroll
        for (int t = 0; t < 4; t++)
            af[t] = *(bf16x8*)&Al[(wm * 64 + t * 16 + lr) * LD + lg * 8];
        #pragma unroll
        for (int t = 0; t < 4; t++)
            bfr[t] = *(bf16x8*)&Bl[(wn * 64 + t * 16 + lr) * LD + lg * 8];
        #pragma unroll
        for (int i = 0; i < 4; i++)
            #pragma unroll
            for (int jn = 0; jn < 4; jn++)
                acc[i][jn] = __builtin_amdgcn_mfma_f32_16x16x32_bf16(af[i], bfr[jn], acc[i][jn], 0, 0, 0);
    }

    #pragma unroll
    for (int jn = 0; jn < 4; jn++) {
        int n = nb * 128 + wn * 64 + jn * 16 + lr;
        float bgv = bg[n];
        #pragma unroll
        for (int i = 0; i < 4; i++) {
            #pragma unroll
            for (int j = 0; j < 4; j++) {
                int mm = mb * 128 + wm * 64 + i * 16 + lg * 4 + j;
                size_t idx = (size_t)mm * 1024 + n;
                float z = acc[i][jn][j] + bgv;
                float gate = 1.f / (1.f + __expf(-z));
                float fv = bf2f((unsigned short)fb[idx]);
                y[idx] = x[idx] + gate * fv;
            }
        }
    }
}

// ---------------- row LayerNorm in place (fp32 -> fp32) ----------------
__global__ __launch_bounds__(256)
void ln_kernel(float* __restrict__ y, const float* __restrict__ gamma,
               const float* __restrict__ beta) {
    int row = blockIdx.x;
    int tid = threadIdx.x;
    float4 v4 = *(const float4*)&y[(size_t)row * 1024 + tid * 4];
    float v[4] = {v4.x, v4.y, v4.z, v4.w};
    float s = v[0] + v[1] + v[2] + v[3];
    float s2 = v[0]*v[0] + v[1]*v[1] + v[2]*v[2] + v[3]*v[3];
    #pragma unroll
    for (int off = 1; off < 64; off <<= 1) {
        s += __shfl_xor(s, off);
        s2 += __shfl_xor(s2, off);
    }
    __shared__ float red[8];
    int wave = tid >> 6, lane = tid & 63;
    if (lane == 0) { red[wave] = s; red[4 + wave] = s2; }
    __syncthreads();
    s = red[0] + red[1] + red[2] + red[3];
    s2 = red[4] + red[5] + red[6] + red[7];
    float mu = s * (1.f / 1024.f);
    float var = s2 * (1.f / 1024.f) - mu * mu;
    float rsq = rsqrtf(var + 1e-5f);
    float4 o4;
    float* o = (float*)&o4;
    #pragma unroll
    for (int e = 0; e < 4; e++) {
        int n = tid * 4 + e;
        o[e] = (v[e] - mu) * rsq * gamma[n] + beta[n];
    }
    *(float4*)&y[(size_t)row * 1024 + tid * 4] = o4;
}

extern "C" void kernel_launch(void* const* d_in, const int* in_sizes, int n_in,
                              void* d_out, int out_size, void* d_ws, size_t ws_size,
                              hipStream_t stream) {
    const float* x     = (const float*)d_in[0];
    const float* Wq    = (const float*)d_in[1];
    const float* bq    = (const float*)d_in[2];
    const float* Wk    = (const float*)d_in[3];
    const float* bk    = (const float*)d_in[4];
    const float* Wv    = (const float*)d_in[5];
    const float* bv    = (const float*)d_in[6];
    const float* Wg    = (const float*)d_in[7];
    const float* bg    = (const float*)d_in[8];
    const float* gamma = (const float*)d_in[9];
    const float* beta  = (const float*)d_in[10];
    float* out = (float*)d_out;   // reference output is fp32 (jax default), NOT bf16

    char* w = (char*)d_ws;
    const size_t MB = 1024 * 1024;
    short* xb  = (short*)(w + 0 * MB);    // [4096][1024] bf16
    short* Qb  = (short*)(w + 8 * MB);
    short* Kb  = (short*)(w + 16 * MB);
    short* Vb  = (short*)(w + 24 * MB);
    short* WT  = (short*)(w + 32 * MB);   // [3072][1024] bf16 (Wq^T|Wk^T|Wv^T)
    short* WgT = (short*)(w + 38 * MB);   // [1024][2048] bf16
    short* fb  = (short*)(w + 42 * MB);   // flowed bf16 [4096][1024]  (ws ends at 50MB)

    cvt_kernel<<<4096, 256, 0, stream>>>(x, xb, 4096 * 1024 / 4);
    dim3 tb(32, 8);
    transpose_bf16<<<dim3(32, 32), tb, 0, stream>>>(Wq, WT, 1024, 1024);
    transpose_bf16<<<dim3(32, 32), tb, 0, stream>>>(Wk, WT + 1024 * 1024, 1024, 1024);
    transpose_bf16<<<dim3(32, 32), tb, 0, stream>>>(Wv, WT + 2 * 1024 * 1024, 1024, 1024);
    transpose_bf16<<<dim3(32, 64), tb, 0, stream>>>(Wg, WgT, 2048, 1024);
    gemm_qkv<<<dim3(32, 24), 256, 0, stream>>>(xb, WT, bq, bk, bv, Qb, Kb, Vb);
    attn_kernel<<<1024, 256, 0, stream>>>(Qb, Kb, Vb, fb);
    gemm_gate<<<dim3(32, 8), 256, 0, stream>>>(xb, fb, WgT, bg, x, out);
    ln_kernel<<<4096, 256, 0, stream>>>(out, gamma, beta);
}